// Round 10
// baseline (134.840 us; speedup 1.0000x reference)
//
#include <hip/hip_runtime.h>
#include <hip/hip_bf16.h>
#include <cstdint>

#define V_N    50000
#define C_N    128
#define COUT_N 256
#define DEG_N  16
#define K2_N   256   // 2*C

typedef short bf16x8 __attribute__((ext_vector_type(8)));
typedef float f32x4  __attribute__((ext_vector_type(4)));
typedef float f32x2  __attribute__((ext_vector_type(2)));

__device__ __forceinline__ unsigned short f2bf(float f) {
    union { float f; unsigned u; } a; a.f = f;
    unsigned r = a.u + 0x7fffu + ((a.u >> 16) & 1u);   // round-to-nearest-even
    return (unsigned short)(r >> 16);
}

// Merged prep: blocks [0,3125) convert data fp32 -> fp8 e4m3 table (6.4MB);
// blocks [3125,3381) transpose+convert kernel weights to bf16 B-fragment order.
__global__ __launch_bounds__(256)
void prep_kernel(const float* __restrict__ data, const float* __restrict__ kern,
                 unsigned* __restrict__ db8, unsigned short* __restrict__ bt) {
    const int b = blockIdx.x;
    if (b < 3125) {
        const int i = b * 256 + threadIdx.x;             // unit of 8 floats; exact
        const float4 f0 = *reinterpret_cast<const float4*>(data + (size_t)i * 8);
        const float4 f1 = *reinterpret_cast<const float4*>(data + (size_t)i * 8 + 4);
        unsigned lo = 0, hi = 0;
        lo = __builtin_amdgcn_cvt_pk_fp8_f32(f0.x, f0.y, lo, false);  // bytes 0,1
        lo = __builtin_amdgcn_cvt_pk_fp8_f32(f0.z, f0.w, lo, true);   // bytes 2,3
        hi = __builtin_amdgcn_cvt_pk_fp8_f32(f1.x, f1.y, hi, false);
        hi = __builtin_amdgcn_cvt_pk_fp8_f32(f1.z, f1.w, hi, true);
        uint2 o; o.x = lo; o.y = hi;
        *reinterpret_cast<uint2*>(db8 + (size_t)i * 2) = o;
    } else {
        // element (n,k) -> bt[(((n>>4)*8+(k>>5))*4+((k>>3)&3))*128 + (n&15)*8 + (k&7)]
        const int k = b - 3125;          // 0..255
        const int n = threadIdx.x;       // 0..255
        const int idx = (((n >> 4) * 8 + (k >> 5)) * 4 + ((k >> 3) & 3)) * 128
                      + (n & 15) * 8 + (k & 7);
        bt[idx] = f2bf(kern[k * COUT_N + n]);
    }
}

// Round 10: batch-8 named-register gathers to force per-wave MLP ~8.
// Diagnosis r9: 200K gather instrs at ~107cy/instr/CU == ~600cy latency with
// only ~2 outstanding gathers/wave (allocator squeezes to VGPR 40 and each
// GATH load is consumed immediately). Fix: 512-thr block, BM=32, ONE row per
// 16-lane group (halves per-group state); edge loop = 2 batches of
// {8 loads into named uint2 regs -> sched_barrier(0) -> 8 decode+FMA}.
// fp8 e4m3 table (128B rows); fp32 x_i from original data (W*x full precision).
// Phase 2: 8 waves (wm 0..1 x wn 0..3), acc[1][4], pre-swizzled global Bt.
// launch_bounds (512,4): proven non-spilling (r4/r5).
__global__ __launch_bounds__(512, 4)
void dgc_fused_kernel(const float* __restrict__ data,
                      const unsigned char* __restrict__ db8,
                      const int* __restrict__ edge_dst,
                      const float* __restrict__ edge_w,
                      const unsigned short* __restrict__ btg,
                      const float* __restrict__ bias,
                      float* __restrict__ out) {
    __shared__ __align__(16) char Asm[32 * 512];   // 16KB

    const int tid  = threadIdx.x;
    const int lane = tid & 63;
    const int wid  = __builtin_amdgcn_readfirstlane(tid >> 6);  // 0..7
    const int m0   = blockIdx.x * 32;
    const int g    = lane >> 4;     // group in wave
    const int c    = lane & 15;     // chunk index (8 channels per lane)

    // ---------------- Phase 1: one vertex row per 16-lane group ----------------
    const int row = wid * 4 + g;                 // 0..31
    const int cv  = min(m0 + row, V_N - 1);      // clamp: tail rows never stored

    const uint4*  ed4 = reinterpret_cast<const uint4*>(edge_dst + (size_t)cv * DEG_N);
    const float4* ew4 = reinterpret_cast<const float4*>(edge_w  + (size_t)cv * DEG_N);

    // self features (fp32, channels c*8 .. c*8+7)
    const float4 xa = *reinterpret_cast<const float4*>(data + (size_t)cv * C_N + c * 8);
    const float4 xb = *reinterpret_cast<const float4*>(data + (size_t)cv * C_N + c * 8 + 4);

    float s[8];
    #pragma unroll
    for (int i = 0; i < 8; ++i) s[i] = 0.f;
    float Ws = 0.f;

    #pragma unroll
    for (int half = 0; half < 2; ++half) {
        // edge meta for this half (16B loads, group-broadcast)
        const uint4  jq0 = ed4[half * 2 + 0];
        const uint4  jq1 = ed4[half * 2 + 1];
        const float4 wq0 = ew4[half * 2 + 0];
        const float4 wq1 = ew4[half * 2 + 1];
        const unsigned jj[8] = { jq0.x, jq0.y, jq0.z, jq0.w,
                                 jq1.x, jq1.y, jq1.z, jq1.w };
        const float    ww[8] = { wq0.x, wq0.y, wq0.z, wq0.w,
                                 wq1.x, wq1.y, wq1.z, wq1.w };

        // batch-issue 8 independent gathers into named regs (MLP = 8)
        uint2 h[8];
        #pragma unroll
        for (int e = 0; e < 8; ++e)
            h[e] = *reinterpret_cast<const uint2*>(
                db8 + (size_t)jj[e] * C_N + c * 8);
        __builtin_amdgcn_sched_barrier(0);   // keep loads clustered above uses

        // batch decode + accumulate (compiler emits counted vmcnt per h[e])
        #pragma unroll
        for (int e = 0; e < 8; ++e) {
            const f32x2 p0 = __builtin_amdgcn_cvt_pk_f32_fp8(h[e].x, false);
            const f32x2 p1 = __builtin_amdgcn_cvt_pk_f32_fp8(h[e].x, true);
            const f32x2 p2 = __builtin_amdgcn_cvt_pk_f32_fp8(h[e].y, false);
            const f32x2 p3 = __builtin_amdgcn_cvt_pk_f32_fp8(h[e].y, true);
            const float wk = ww[e];
            s[0] = fmaf(wk, p0[0], s[0]);
            s[1] = fmaf(wk, p0[1], s[1]);
            s[2] = fmaf(wk, p1[0], s[2]);
            s[3] = fmaf(wk, p1[1], s[3]);
            s[4] = fmaf(wk, p2[0], s[4]);
            s[5] = fmaf(wk, p2[1], s[5]);
            s[6] = fmaf(wk, p3[0], s[6]);
            s[7] = fmaf(wk, p3[1], s[7]);
        }
        Ws += ((ww[0] + ww[1]) + (ww[2] + ww[3]))
            + ((ww[4] + ww[5]) + (ww[6] + ww[7]));
    }

    // Pack u = W*x (k<128) and v = s - W*x (k>=128); write swizzled A row.
    {
        float u[8], v[8];
        u[0] = Ws * xa.x; u[1] = Ws * xa.y; u[2] = Ws * xa.z; u[3] = Ws * xa.w;
        u[4] = Ws * xb.x; u[5] = Ws * xb.y; u[6] = Ws * xb.z; u[7] = Ws * xb.w;
        #pragma unroll
        for (int i = 0; i < 8; ++i) v[i] = s[i] - u[i];
        uint4 up, vp;
        up.x = (unsigned)f2bf(u[0]) | ((unsigned)f2bf(u[1]) << 16);
        up.y = (unsigned)f2bf(u[2]) | ((unsigned)f2bf(u[3]) << 16);
        up.z = (unsigned)f2bf(u[4]) | ((unsigned)f2bf(u[5]) << 16);
        up.w = (unsigned)f2bf(u[6]) | ((unsigned)f2bf(u[7]) << 16);
        vp.x = (unsigned)f2bf(v[0]) | ((unsigned)f2bf(v[1]) << 16);
        vp.y = (unsigned)f2bf(v[2]) | ((unsigned)f2bf(v[3]) << 16);
        vp.z = (unsigned)f2bf(v[4]) | ((unsigned)f2bf(v[5]) << 16);
        vp.w = (unsigned)f2bf(v[6]) | ((unsigned)f2bf(v[7]) << 16);
        const int sw = row & 7;
        char* rowp = Asm + row * 512;
        *reinterpret_cast<uint4*>(rowp + ((c        ^ sw) * 16)) = up;
        *reinterpret_cast<uint4*>(rowp + (((16 + c) ^ sw) * 16)) = vp;
    }
    __syncthreads();

    // ---------------- Phase 2: A[32x256] @ K[256x256], 8 waves x (16x64) ----------------
    const int wm = wid >> 2;   // 0..1 : 16-row wave tile
    const int wn = wid & 3;    // 0..3 : 64-col wave tile

    f32x4 acc[4];
    #pragma unroll
    for (int nf = 0; nf < 4; ++nf)
        acc[nf] = (f32x4){0.f, 0.f, 0.f, 0.f};

    #pragma unroll
    for (int ks = 0; ks < 8; ++ks) {     // K = 256 = 8 * 32
        bf16x8 a, b[4];
        {
            const int r  = wm * 16 + c;
            const int ck = (ks * 4 + g) ^ (r & 7);
            a = *reinterpret_cast<const bf16x8*>(Asm + r * 512 + ck * 16);
        }
        #pragma unroll
        for (int nf = 0; nf < 4; ++nf) {
            const int nb = wn * 4 + nf;
            b[nf] = *reinterpret_cast<const bf16x8*>(
                btg + (size_t)((nb * 32 + ks * 4 + g) * 16 + c) * 8);  // lane-linear 1KB
        }
        #pragma unroll
        for (int nf = 0; nf < 4; ++nf)
            acc[nf] = __builtin_amdgcn_mfma_f32_16x16x32_bf16(a, b[nf], acc[nf], 0, 0, 0);
    }

    // Epilogue: C/D layout col = lane&15, row = (lane>>4)*4 + reg. bias ok (Σw==1).
    {
        const int row_l = wm * 16 + g * 4;
        #pragma unroll
        for (int nf = 0; nf < 4; ++nf) {
            const int col = wn * 64 + nf * 16 + c;
            const float bb = bias[col];
            #pragma unroll
            for (int r = 0; r < 4; ++r) {
                const int rg = m0 + row_l + r;
                if (rg < V_N)
                    out[(size_t)rg * COUT_N + col] = acc[nf][r] + bb;
            }
        }
    }
}

extern "C" void kernel_launch(void* const* d_in, const int* in_sizes, int n_in,
                              void* d_out, int out_size, void* d_ws, size_t ws_size,
                              hipStream_t stream) {
    const float* data     = (const float*)d_in[0];
    // d_in[1] = edge_src: implicit (vertex i owns edges [16i,16i+16)), unused
    const int*   edge_dst = (const int*)d_in[2];
    const float* edge_w   = (const float*)d_in[3];
    const float* kern     = (const float*)d_in[4];
    const float* bias     = (const float*)d_in[5];
    float*       out      = (float*)d_out;

    unsigned short* bt  = (unsigned short*)d_ws;                 // 128KB bf16 B-frags
    unsigned char*  db8 = (unsigned char*)d_ws + 131072;         // 6.4MB fp8 table

    prep_kernel<<<3125 + 256, 256, 0, stream>>>(data, kern, (unsigned*)db8, bt);

    const int nblk = (V_N + 31) / 32;   // 1563
    dgc_fused_kernel<<<nblk, 512, 0, stream>>>(data, db8, edge_dst, edge_w, bt, bias, out);
}

// Round 11
// 127.446 us; speedup vs baseline: 1.0580x; 1.0580x over previous
//
#include <hip/hip_runtime.h>
#include <hip/hip_bf16.h>
#include <cstdint>

#define V_N    50000
#define C_N    128
#define COUT_N 256
#define DEG_N  16
#define K2_N   256   // 2*C

typedef short bf16x8 __attribute__((ext_vector_type(8)));
typedef float f32x4  __attribute__((ext_vector_type(4)));
typedef float f32x2  __attribute__((ext_vector_type(2)));

__device__ __forceinline__ unsigned short f2bf(float f) {
    union { float f; unsigned u; } a; a.f = f;
    unsigned r = a.u + 0x7fffu + ((a.u >> 16) & 1u);   // round-to-nearest-even
    return (unsigned short)(r >> 16);
}

// Merged prep: blocks [0,3125) convert data fp32 -> fp8 e4m3 table (6.4MB);
// blocks [3125,3381) transpose+convert kernel weights to bf16 B-fragment order.
__global__ __launch_bounds__(256)
void prep_kernel(const float* __restrict__ data, const float* __restrict__ kern,
                 unsigned* __restrict__ db8, unsigned short* __restrict__ bt) {
    const int b = blockIdx.x;
    if (b < 3125) {
        const int i = b * 256 + threadIdx.x;             // unit of 8 floats; exact
        const float4 f0 = *reinterpret_cast<const float4*>(data + (size_t)i * 8);
        const float4 f1 = *reinterpret_cast<const float4*>(data + (size_t)i * 8 + 4);
        unsigned lo = 0, hi = 0;
        lo = __builtin_amdgcn_cvt_pk_fp8_f32(f0.x, f0.y, lo, false);  // bytes 0,1
        lo = __builtin_amdgcn_cvt_pk_fp8_f32(f0.z, f0.w, lo, true);   // bytes 2,3
        hi = __builtin_amdgcn_cvt_pk_fp8_f32(f1.x, f1.y, hi, false);
        hi = __builtin_amdgcn_cvt_pk_fp8_f32(f1.z, f1.w, hi, true);
        uint2 o; o.x = lo; o.y = hi;
        *reinterpret_cast<uint2*>(db8 + (size_t)i * 2) = o;
    } else {
        // element (n,k) -> bt[(((n>>4)*8+(k>>5))*4+((k>>3)&3))*128 + (n&15)*8 + (k&7)]
        const int k = b - 3125;          // 0..255
        const int n = threadIdx.x;       // 0..255
        const int idx = (((n >> 4) * 8 + (k >> 5)) * 4 + ((k >> 3) & 3)) * 128
                      + (n & 15) * 8 + (k & 7);
        bt[idx] = f2bf(kern[k * COUT_N + n]);
    }
}

// Round 11 = round-9 structure with the gather unit widened to 8-lane x uint4:
// one wave-instr covers 8 random fp8 rows (1KB) instead of 4 -> 100K wave-gather
// instrs total (half of r9). Model from r7/r9/r10: time ~ a*instrs + b*bytes;
// bytes part is ~7us at fp8, the ~35us residual tracks instruction count.
// Each 8-lane group owns ONE vertex row; lane decodes 16 channels (s[16]).
// Direct consumption, no sched fences (r10 proved fences hurt). fp32 x_i from
// original data (W*x path full precision). 256 thr, BM=32, A-tile 16KB swizzled;
// phase 2 (MFMA vs pre-swizzled global Bt) and epilogue verbatim from r9.
__global__ __launch_bounds__(256, 4)
void dgc_fused_kernel(const float* __restrict__ data,
                      const unsigned char* __restrict__ db8,
                      const int* __restrict__ edge_dst,
                      const float* __restrict__ edge_w,
                      const unsigned short* __restrict__ btg,
                      const float* __restrict__ bias,
                      float* __restrict__ out) {
    __shared__ __align__(16) char Asm[32 * 512];   // 16KB

    const int tid  = threadIdx.x;
    const int lane = tid & 63;
    const int wid  = __builtin_amdgcn_readfirstlane(tid >> 6);  // 0..3
    const int m0   = blockIdx.x * 32;

    // ---------------- Phase 1: one vertex row per 8-lane group ----------------
    const int g8 = lane >> 3;     // 0..7 : group in wave
    const int c8 = lane & 7;      // 16B unit within a 128B fp8 row (16 channels)

    const int row = wid * 8 + g8;                // 0..31
    const int cv  = min(m0 + row, V_N - 1);      // clamp: tail rows never stored

    const uint4*  ed4 = reinterpret_cast<const uint4*>(edge_dst + (size_t)cv * DEG_N);
    const float4* ew4 = reinterpret_cast<const float4*>(edge_w  + (size_t)cv * DEG_N);

    // self features (fp32, channels c8*16 .. c8*16+15) — 512B/group, coalesced
    const float4* xp = reinterpret_cast<const float4*>(data + (size_t)cv * C_N + c8 * 16);
    const float4 x0 = xp[0], x1 = xp[1], x2 = xp[2], x3 = xp[3];

    float s[16];
    #pragma unroll
    for (int i = 0; i < 16; ++i) s[i] = 0.f;
    float Ws = 0.f;

#define GATH(J, WK)                                                           \
    do {                                                                      \
        const uint4 h = *reinterpret_cast<const uint4*>(                      \
            db8 + (size_t)(J) * C_N + c8 * 16);                               \
        const f32x2 p0 = __builtin_amdgcn_cvt_pk_f32_fp8(h.x, false);         \
        const f32x2 p1 = __builtin_amdgcn_cvt_pk_f32_fp8(h.x, true);          \
        const f32x2 p2 = __builtin_amdgcn_cvt_pk_f32_fp8(h.y, false);         \
        const f32x2 p3 = __builtin_amdgcn_cvt_pk_f32_fp8(h.y, true);          \
        const f32x2 p4 = __builtin_amdgcn_cvt_pk_f32_fp8(h.z, false);         \
        const f32x2 p5 = __builtin_amdgcn_cvt_pk_f32_fp8(h.z, true);          \
        const f32x2 p6 = __builtin_amdgcn_cvt_pk_f32_fp8(h.w, false);         \
        const f32x2 p7 = __builtin_amdgcn_cvt_pk_f32_fp8(h.w, true);          \
        s[ 0] = fmaf((WK), p0[0], s[ 0]);  s[ 1] = fmaf((WK), p0[1], s[ 1]);  \
        s[ 2] = fmaf((WK), p1[0], s[ 2]);  s[ 3] = fmaf((WK), p1[1], s[ 3]);  \
        s[ 4] = fmaf((WK), p2[0], s[ 4]);  s[ 5] = fmaf((WK), p2[1], s[ 5]);  \
        s[ 6] = fmaf((WK), p3[0], s[ 6]);  s[ 7] = fmaf((WK), p3[1], s[ 7]);  \
        s[ 8] = fmaf((WK), p4[0], s[ 8]);  s[ 9] = fmaf((WK), p4[1], s[ 9]);  \
        s[10] = fmaf((WK), p5[0], s[10]);  s[11] = fmaf((WK), p5[1], s[11]);  \
        s[12] = fmaf((WK), p6[0], s[12]);  s[13] = fmaf((WK), p6[1], s[13]);  \
        s[14] = fmaf((WK), p7[0], s[14]);  s[15] = fmaf((WK), p7[1], s[15]);  \
    } while (0)

    #pragma unroll
    for (int kq = 0; kq < 4; ++kq) {
        const uint4  jq = ed4[kq];
        const float4 wq = ew4[kq];
        GATH(jq.x, wq.x);
        GATH(jq.y, wq.y);
        GATH(jq.z, wq.z);
        GATH(jq.w, wq.w);
        Ws += (wq.x + wq.y) + (wq.z + wq.w);
    }
#undef GATH

    // Pack u = W*x (k<128) and v = s - W*x (k>=128); write swizzled A row.
    {
        float u[16], v[16];
        u[ 0] = Ws * x0.x; u[ 1] = Ws * x0.y; u[ 2] = Ws * x0.z; u[ 3] = Ws * x0.w;
        u[ 4] = Ws * x1.x; u[ 5] = Ws * x1.y; u[ 6] = Ws * x1.z; u[ 7] = Ws * x1.w;
        u[ 8] = Ws * x2.x; u[ 9] = Ws * x2.y; u[10] = Ws * x2.z; u[11] = Ws * x2.w;
        u[12] = Ws * x3.x; u[13] = Ws * x3.y; u[14] = Ws * x3.z; u[15] = Ws * x3.w;
        #pragma unroll
        for (int i = 0; i < 16; ++i) v[i] = s[i] - u[i];
        uint4 up0, up1, vp0, vp1;
        up0.x = (unsigned)f2bf(u[ 0]) | ((unsigned)f2bf(u[ 1]) << 16);
        up0.y = (unsigned)f2bf(u[ 2]) | ((unsigned)f2bf(u[ 3]) << 16);
        up0.z = (unsigned)f2bf(u[ 4]) | ((unsigned)f2bf(u[ 5]) << 16);
        up0.w = (unsigned)f2bf(u[ 6]) | ((unsigned)f2bf(u[ 7]) << 16);
        up1.x = (unsigned)f2bf(u[ 8]) | ((unsigned)f2bf(u[ 9]) << 16);
        up1.y = (unsigned)f2bf(u[10]) | ((unsigned)f2bf(u[11]) << 16);
        up1.z = (unsigned)f2bf(u[12]) | ((unsigned)f2bf(u[13]) << 16);
        up1.w = (unsigned)f2bf(u[14]) | ((unsigned)f2bf(u[15]) << 16);
        vp0.x = (unsigned)f2bf(v[ 0]) | ((unsigned)f2bf(v[ 1]) << 16);
        vp0.y = (unsigned)f2bf(v[ 2]) | ((unsigned)f2bf(v[ 3]) << 16);
        vp0.z = (unsigned)f2bf(v[ 4]) | ((unsigned)f2bf(v[ 5]) << 16);
        vp0.w = (unsigned)f2bf(v[ 6]) | ((unsigned)f2bf(v[ 7]) << 16);
        vp1.x = (unsigned)f2bf(v[ 8]) | ((unsigned)f2bf(v[ 9]) << 16);
        vp1.y = (unsigned)f2bf(v[10]) | ((unsigned)f2bf(v[11]) << 16);
        vp1.z = (unsigned)f2bf(v[12]) | ((unsigned)f2bf(v[13]) << 16);
        vp1.w = (unsigned)f2bf(v[14]) | ((unsigned)f2bf(v[15]) << 16);
        const int sw = row & 7;
        char* rowp = Asm + row * 512;
        *reinterpret_cast<uint4*>(rowp + (((2 * c8 + 0)      ^ sw) * 16)) = up0;
        *reinterpret_cast<uint4*>(rowp + (((2 * c8 + 1)      ^ sw) * 16)) = up1;
        *reinterpret_cast<uint4*>(rowp + (((16 + 2 * c8 + 0) ^ sw) * 16)) = vp0;
        *reinterpret_cast<uint4*>(rowp + (((16 + 2 * c8 + 1) ^ sw) * 16)) = vp1;
    }
    __syncthreads();

    // ---------------- Phase 2: A[32x256] @ K[256x256], wave = 32x64 tile ----------------
    const int g  = lane >> 4;   // k-slice index
    const int c  = lane & 15;   // 16B chunk index
    const int wn = wid;         // 0..3 : 64-col wave tile

    f32x4 acc[2][4];
    #pragma unroll
    for (int mf = 0; mf < 2; ++mf)
        #pragma unroll
        for (int nf = 0; nf < 4; ++nf)
            acc[mf][nf] = (f32x4){0.f, 0.f, 0.f, 0.f};

    #pragma unroll
    for (int ks = 0; ks < 8; ++ks) {     // K = 256 = 8 * 32
        bf16x8 a[2], b[4];
        #pragma unroll
        for (int mf = 0; mf < 2; ++mf) {
            const int r  = mf * 16 + c;
            const int ck = (ks * 4 + g) ^ (r & 7);
            a[mf] = *reinterpret_cast<const bf16x8*>(Asm + r * 512 + ck * 16);
        }
        #pragma unroll
        for (int nf = 0; nf < 4; ++nf) {
            const int nb = wn * 4 + nf;
            b[nf] = *reinterpret_cast<const bf16x8*>(
                btg + (size_t)((nb * 32 + ks * 4 + g) * 16 + c) * 8);  // lane-linear 1KB
        }
        #pragma unroll
        for (int mf = 0; mf < 2; ++mf)
            #pragma unroll
            for (int nf = 0; nf < 4; ++nf)
                acc[mf][nf] = __builtin_amdgcn_mfma_f32_16x16x32_bf16(
                    a[mf], b[nf], acc[mf][nf], 0, 0, 0);
    }

    // Epilogue: C/D layout col = lane&15, row = (lane>>4)*4 + reg. bias ok (Σw==1).
    #pragma unroll
    for (int mf = 0; mf < 2; ++mf) {
        const int row_l = mf * 16 + g * 4;
        #pragma unroll
        for (int nf = 0; nf < 4; ++nf) {
            const int col = wn * 64 + nf * 16 + c;
            const float bb = bias[col];
            #pragma unroll
            for (int r = 0; r < 4; ++r) {
                const int rg = m0 + row_l + r;
                if (rg < V_N)
                    out[(size_t)rg * COUT_N + col] = acc[mf][nf][r] + bb;
            }
        }
    }
}

extern "C" void kernel_launch(void* const* d_in, const int* in_sizes, int n_in,
                              void* d_out, int out_size, void* d_ws, size_t ws_size,
                              hipStream_t stream) {
    const float* data     = (const float*)d_in[0];
    // d_in[1] = edge_src: implicit (vertex i owns edges [16i,16i+16)), unused
    const int*   edge_dst = (const int*)d_in[2];
    const float* edge_w   = (const float*)d_in[3];
    const float* kern     = (const float*)d_in[4];
    const float* bias     = (const float*)d_in[5];
    float*       out      = (float*)d_out;

    unsigned short* bt  = (unsigned short*)d_ws;                 // 128KB bf16 B-frags
    unsigned char*  db8 = (unsigned char*)d_ws + 131072;         // 6.4MB fp8 table

    prep_kernel<<<3125 + 256, 256, 0, stream>>>(data, kern, (unsigned*)db8, bt);

    const int nblk = (V_N + 31) / 32;   // 1563
    dgc_fused_kernel<<<nblk, 256, 0, stream>>>(data, db8, edge_dst, edge_w, bt, bias, out);
}